// Round 1
// baseline (595.786 us; speedup 1.0000x reference)
//
#include <hip/hip_runtime.h>

#define T_DIM 16384
#define H_DIM 2048
#define I_DIM 1408

typedef _Float16 half8 __attribute__((ext_vector_type(8)));
typedef float floatx4 __attribute__((ext_vector_type(4)));

static_assert(T_DIM % 128 == 0 && H_DIM % 128 == 0 && I_DIM % 128 == 0, "tile divisibility");

// -------- async global -> LDS, 16 bytes per lane (gfx950) --------
__device__ __forceinline__ void async_cp16(const _Float16* gp, _Float16* lp) {
    __builtin_amdgcn_global_load_lds(
        (const __attribute__((address_space(1))) unsigned int*)gp,
        (__attribute__((address_space(3))) unsigned int*)lp,
        16, 0, 0);
}

// -------- fp32 -> fp16 conversion of x --------
__global__ void cvt_fp16_kernel(const float* __restrict__ x, _Float16* __restrict__ xh) {
    int i = (blockIdx.x * 256 + threadIdx.x) * 8;
    const float4* p = (const float4*)(x + i);
    float4 a = p[0];
    float4 b = p[1];
    half8 o = { (_Float16)a.x, (_Float16)a.y, (_Float16)a.z, (_Float16)a.w,
                (_Float16)b.x, (_Float16)b.y, (_Float16)b.z, (_Float16)b.w };
    *(half8*)(xh + i) = o;
}

// -------- GPTQ dequant -> transposed fp16 weight Wt[n][k] --------
// qw: [K/8][N] int32 (8 nibbles along k), qz: [K/128][N/8] int32, sc: [K/128][N] f32
__global__ void dequant_kernel(const int* __restrict__ qw, const int* __restrict__ qz,
                               const float* __restrict__ sc, _Float16* __restrict__ Wt,
                               int K, int N) {
    int kp = blockIdx.x * 64 + threadIdx.x;   // packed-k index [0, K/8)
    int n  = blockIdx.y;
    if (kp >= (K >> 3)) return;
    int q = qw[kp * N + n];
    int g = kp >> 4;                           // (kp*8)/128
    float scale = sc[g * N + n];
    int zq = (qz[g * (N >> 3) + (n >> 3)] >> (4 * (n & 7))) & 0xF;
    float zf = (float)(zq + 1);
    half8 o;
#pragma unroll
    for (int j = 0; j < 8; ++j) {
        float w = ((float)((q >> (4 * j)) & 0xF) - zf) * scale;
        o[j] = (_Float16)w;
    }
    *(half8*)(Wt + n * K + kp * 8) = o;        // 16B coalesced store (consecutive kp)
}

// -------- GEMM1: h = silu(x@Wg) * (x@Wu), fused, fp16 out --------
// A = xh [T][H], B = Wg_t/Wu_t [I][H] (k-contiguous rows), 128x128 tile, BK=32
__launch_bounds__(256, 2)
__global__ void gemm_gateup_kernel(const _Float16* __restrict__ xh,
                                   const _Float16* __restrict__ Wg,
                                   const _Float16* __restrict__ Wu,
                                   _Float16* __restrict__ h) {
    __shared__ _Float16 As[128 * 32];
    __shared__ _Float16 Bgs[128 * 32];
    __shared__ _Float16 Bus[128 * 32];

    const int tid  = threadIdx.x;
    const int wave = tid >> 6;
    const int lane = tid & 63;
    const int m0 = blockIdx.y * 128;
    const int n0 = blockIdx.x * 128;
    const int wm = wave >> 1;       // wave row (2x2 wave grid, each wave 64x64)
    const int wn = wave & 1;        // wave col

    // staging: per wave 2 issues of 1KB (16 rows x 64B); lane l -> row l/4, 16B chunk l%4
    const int r0 = wave * 32 + (lane >> 2);
    const int ke = (lane & 3) * 8;
    const _Float16* agp0 = xh + (m0 + r0) * H_DIM + ke;
    const _Float16* agp1 = agp0 + 16 * H_DIM;
    const _Float16* bgp0 = Wg + (n0 + r0) * H_DIM + ke;
    const _Float16* bgp1 = bgp0 + 16 * H_DIM;
    const _Float16* bup0 = Wu + (n0 + r0) * H_DIM + ke;
    const _Float16* bup1 = bup0 + 16 * H_DIM;
    _Float16* lA0  = As  + wave * 1024;        // (wave*2+0)*512 elems = 1KB chunks
    _Float16* lA1  = As  + wave * 1024 + 512;
    _Float16* lBg0 = Bgs + wave * 1024;
    _Float16* lBg1 = Bgs + wave * 1024 + 512;
    _Float16* lBu0 = Bus + wave * 1024;
    _Float16* lBu1 = Bus + wave * 1024 + 512;

    // MFMA fragment addresses: A[m=lane&15][k=(lane>>4)*8 + j]
    const int q4  = lane >> 4;
    const int l15 = lane & 15;
    const int a_base = (wm * 64 + l15) * 32 + q4 * 8;
    const int b_base = (wn * 64 + l15) * 32 + q4 * 8;

    floatx4 zero = {0.f, 0.f, 0.f, 0.f};
    floatx4 accg[4][4], accu[4][4];
#pragma unroll
    for (int mi = 0; mi < 4; ++mi)
#pragma unroll
        for (int ni = 0; ni < 4; ++ni) { accg[mi][ni] = zero; accu[mi][ni] = zero; }

    for (int kt = 0; kt < H_DIM; kt += 32) {
        __syncthreads();
        async_cp16(agp0 + kt, lA0);
        async_cp16(agp1 + kt, lA1);
        async_cp16(bgp0 + kt, lBg0);
        async_cp16(bgp1 + kt, lBg1);
        async_cp16(bup0 + kt, lBu0);
        async_cp16(bup1 + kt, lBu1);
        __syncthreads();

        half8 af[4], bgf[4], buf_[4];
#pragma unroll
        for (int mi = 0; mi < 4; ++mi)
            af[mi] = *(const half8*)(As + a_base + mi * 512);
#pragma unroll
        for (int ni = 0; ni < 4; ++ni) {
            bgf[ni]  = *(const half8*)(Bgs + b_base + ni * 512);
            buf_[ni] = *(const half8*)(Bus + b_base + ni * 512);
        }
#pragma unroll
        for (int mi = 0; mi < 4; ++mi)
#pragma unroll
            for (int ni = 0; ni < 4; ++ni) {
                accg[mi][ni] = __builtin_amdgcn_mfma_f32_16x16x32_f16(af[mi], bgf[ni], accg[mi][ni], 0, 0, 0);
                accu[mi][ni] = __builtin_amdgcn_mfma_f32_16x16x32_f16(af[mi], buf_[ni], accu[mi][ni], 0, 0, 0);
            }
    }

    // epilogue: C/D layout col=lane&15, row=(lane>>4)*4+r
    const int rq = q4 * 4;
#pragma unroll
    for (int mi = 0; mi < 4; ++mi)
#pragma unroll
        for (int ni = 0; ni < 4; ++ni)
#pragma unroll
            for (int r = 0; r < 4; ++r) {
                int row = m0 + wm * 64 + mi * 16 + rq + r;
                int col = n0 + wn * 64 + ni * 16 + l15;
                float g = accg[mi][ni][r];
                float u = accu[mi][ni][r];
                float s = (g / (1.0f + __expf(-g))) * u;   // silu(g) * u
                h[row * I_DIM + col] = (_Float16)s;
            }
}

// -------- GEMM2: out = h @ Wd, fp32 out --------
// A = h [T][I], B = Wd_t [H][I], K = I_DIM
__launch_bounds__(256, 2)
__global__ void gemm_down_kernel(const _Float16* __restrict__ hh,
                                 const _Float16* __restrict__ Wd,
                                 float* __restrict__ out) {
    __shared__ _Float16 As[128 * 32];
    __shared__ _Float16 Bs[128 * 32];

    const int tid  = threadIdx.x;
    const int wave = tid >> 6;
    const int lane = tid & 63;
    const int m0 = blockIdx.y * 128;
    const int n0 = blockIdx.x * 128;
    const int wm = wave >> 1;
    const int wn = wave & 1;

    const int r0 = wave * 32 + (lane >> 2);
    const int ke = (lane & 3) * 8;
    const _Float16* agp0 = hh + (m0 + r0) * I_DIM + ke;
    const _Float16* agp1 = agp0 + 16 * I_DIM;
    const _Float16* bgp0 = Wd + (n0 + r0) * I_DIM + ke;
    const _Float16* bgp1 = bgp0 + 16 * I_DIM;
    _Float16* lA0 = As + wave * 1024;
    _Float16* lA1 = As + wave * 1024 + 512;
    _Float16* lB0 = Bs + wave * 1024;
    _Float16* lB1 = Bs + wave * 1024 + 512;

    const int q4  = lane >> 4;
    const int l15 = lane & 15;
    const int a_base = (wm * 64 + l15) * 32 + q4 * 8;
    const int b_base = (wn * 64 + l15) * 32 + q4 * 8;

    floatx4 zero = {0.f, 0.f, 0.f, 0.f};
    floatx4 acc[4][4];
#pragma unroll
    for (int mi = 0; mi < 4; ++mi)
#pragma unroll
        for (int ni = 0; ni < 4; ++ni) acc[mi][ni] = zero;

    for (int kt = 0; kt < I_DIM; kt += 32) {
        __syncthreads();
        async_cp16(agp0 + kt, lA0);
        async_cp16(agp1 + kt, lA1);
        async_cp16(bgp0 + kt, lB0);
        async_cp16(bgp1 + kt, lB1);
        __syncthreads();

        half8 af[4], bf[4];
#pragma unroll
        for (int mi = 0; mi < 4; ++mi)
            af[mi] = *(const half8*)(As + a_base + mi * 512);
#pragma unroll
        for (int ni = 0; ni < 4; ++ni)
            bf[ni] = *(const half8*)(Bs + b_base + ni * 512);
#pragma unroll
        for (int mi = 0; mi < 4; ++mi)
#pragma unroll
            for (int ni = 0; ni < 4; ++ni)
                acc[mi][ni] = __builtin_amdgcn_mfma_f32_16x16x32_f16(af[mi], bf[ni], acc[mi][ni], 0, 0, 0);
    }

    const int rq = q4 * 4;
#pragma unroll
    for (int mi = 0; mi < 4; ++mi)
#pragma unroll
        for (int ni = 0; ni < 4; ++ni)
#pragma unroll
            for (int r = 0; r < 4; ++r) {
                int row = m0 + wm * 64 + mi * 16 + rq + r;
                int col = n0 + wn * 64 + ni * 16 + l15;
                out[row * H_DIM + col] = acc[mi][ni][r];
            }
}

extern "C" void kernel_launch(void* const* d_in, const int* in_sizes, int n_in,
                              void* d_out, int out_size, void* d_ws, size_t ws_size,
                              hipStream_t stream) {
    const float* x    = (const float*)d_in[0];
    const int* qw_g   = (const int*)d_in[1];
    const int* qz_g   = (const int*)d_in[2];
    const float* sc_g = (const float*)d_in[3];
    const int* qw_u   = (const int*)d_in[4];
    const int* qz_u   = (const int*)d_in[5];
    const float* sc_u = (const float*)d_in[6];
    const int* qw_d   = (const int*)d_in[7];
    const int* qz_d   = (const int*)d_in[8];
    const float* sc_d = (const float*)d_in[9];
    float* out = (float*)d_out;

    // workspace layout (fp16): xh 64MB | h 44MB | Wg_t | Wu_t | Wd_t (5.5MB each) = ~124.5MB
    char* ws = (char*)d_ws;
    _Float16* xh = (_Float16*)ws;  ws += (size_t)T_DIM * H_DIM * sizeof(_Float16);
    _Float16* hh = (_Float16*)ws;  ws += (size_t)T_DIM * I_DIM * sizeof(_Float16);
    _Float16* Wg = (_Float16*)ws;  ws += (size_t)H_DIM * I_DIM * sizeof(_Float16);
    _Float16* Wu = (_Float16*)ws;  ws += (size_t)H_DIM * I_DIM * sizeof(_Float16);
    _Float16* Wd = (_Float16*)ws;  ws += (size_t)I_DIM * H_DIM * sizeof(_Float16);

    cvt_fp16_kernel<<<(T_DIM * H_DIM) / 2048, 256, 0, stream>>>(x, xh);
    dequant_kernel<<<dim3((H_DIM / 8 + 63) / 64, I_DIM), 64, 0, stream>>>(qw_g, qz_g, sc_g, Wg, H_DIM, I_DIM);
    dequant_kernel<<<dim3((H_DIM / 8 + 63) / 64, I_DIM), 64, 0, stream>>>(qw_u, qz_u, sc_u, Wu, H_DIM, I_DIM);
    dequant_kernel<<<dim3((I_DIM / 8 + 63) / 64, H_DIM), 64, 0, stream>>>(qw_d, qz_d, sc_d, Wd, I_DIM, H_DIM);
    gemm_gateup_kernel<<<dim3(I_DIM / 128, T_DIM / 128), 256, 0, stream>>>(xh, Wg, Wu, hh);
    gemm_down_kernel<<<dim3(H_DIM / 128, T_DIM / 128), 256, 0, stream>>>(hh, Wd, out);
}

// Round 2
// 518.106 us; speedup vs baseline: 1.1499x; 1.1499x over previous
//
#include <hip/hip_runtime.h>

#define T_DIM 16384
#define H_DIM 2048
#define I_DIM 1408
#define NB_DIM (2 * I_DIM)   // 2816 interleaved gate/up columns

typedef _Float16 half8 __attribute__((ext_vector_type(8)));
typedef float floatx4 __attribute__((ext_vector_type(4)));

// -------- async global -> LDS, 16 bytes per lane (gfx950) --------
// NOTE: LDS dest is wave-uniform base; HW writes lane l at base + l*16.
__device__ __forceinline__ void async_cp16(const _Float16* gp, _Float16* lp) {
    __builtin_amdgcn_global_load_lds(
        (const __attribute__((address_space(1))) unsigned int*)gp,
        (__attribute__((address_space(3))) unsigned int*)lp,
        16, 0, 0);
}

// -------- fp32 -> fp16 conversion of x --------
__global__ void cvt_fp16_kernel(const float* __restrict__ x, _Float16* __restrict__ xh) {
    int i = (blockIdx.x * 256 + threadIdx.x) * 8;
    const float4* p = (const float4*)(x + i);
    float4 a = p[0];
    float4 b = p[1];
    half8 o = { (_Float16)a.x, (_Float16)a.y, (_Float16)a.z, (_Float16)a.w,
                (_Float16)b.x, (_Float16)b.y, (_Float16)b.z, (_Float16)b.w };
    *(half8*)(xh + i) = o;
}

// -------- GPTQ dequant -> transposed fp16 weight Wt[n'][k], coalesced both ways --------
// qw: [K/8][N] int32 (8 nibbles along k), qz: [K/128][N/8] int32, sc: [K/128][N] f32
// interleave: n' = (n>>5)*64 + (n&31) + off  (gate off=0, up off=32); else n' = n.
__global__ void dequant_kernel(const int* __restrict__ qw, const int* __restrict__ qz,
                               const float* __restrict__ sc, _Float16* __restrict__ Wt,
                               int K, int N, int interleave, int off) {
    __shared__ half8 tile[256];                 // [64 n][4 kp]
    int t = threadIdx.x;
    int nl = t & 63, kl = t >> 6;
    int n  = blockIdx.x * 64 + nl;
    int kp = blockIdx.y * 4 + kl;
    int q = qw[kp * N + n];                     // coalesced along n
    int g = kp >> 4;                            // (kp*8)/128
    float scale = sc[g * N + n];
    int zq = (qz[g * (N >> 3) + (n >> 3)] >> (4 * (n & 7))) & 0xF;
    float zf = (float)(zq + 1);
    half8 o;
#pragma unroll
    for (int j = 0; j < 8; ++j)
        o[j] = (_Float16)(((float)((q >> (4 * j)) & 0xF) - zf) * scale);
    tile[nl * 4 + kl] = o;
    __syncthreads();
    int nl2 = t >> 2, kl2 = t & 3;
    int n2 = blockIdx.x * 64 + nl2;
    int np = interleave ? (((n2 >> 5) << 6) + (n2 & 31) + off) : n2;
    *(half8*)(Wt + (size_t)np * K + (size_t)(blockIdx.y * 4 + kl2) * 8) = tile[nl2 * 4 + kl2];
}

// ============ shared GEMM structure: 128x128 tile, BK=64, XOR-swizzled LDS ============
// LDS row = 128B (8 chunks of 16B); chunk c of row r stored at position c ^ (r&7).
// Staging: issue i covers rows [i*32, i*32+32); lane l of wave w loads global chunk
// (l&7)^(l>>3) of row i*32 + w*8 + (l>>3); HW lands it at stored position l&7. 4-way
// frag reads then hit all 32 banks per 8-lane phase (2-way over 16 lanes = free).

// -------- GEMM1: h = silu(gate) * up via interleaved B' [2816][2048], fp16 out --------
__launch_bounds__(256, 3)
__global__ void gemm_gateup(const _Float16* __restrict__ A,   // xh [T][H]
                            const _Float16* __restrict__ B,   // B'  [2816][H]
                            _Float16* __restrict__ h) {       // [T][I]
    __shared__ _Float16 As[128 * 64];
    __shared__ _Float16 Bs[128 * 64];
    const int t = threadIdx.x;
    const int wave = t >> 6, lane = t & 63;
    const int m0 = blockIdx.x * 128;            // rows fastest for L2 reuse of B'
    const int n0 = blockIdx.y * 128;
    const int wm = wave >> 1, wn = wave & 1;

    const int srow = wave * 8 + (lane >> 3);
    const int schunk = (lane & 7) ^ (lane >> 3);
    const _Float16* ag = A + (size_t)(m0 + srow) * H_DIM + schunk * 8;
    const _Float16* bg = B + (size_t)(n0 + srow) * H_DIM + schunk * 8;
    _Float16* lA = As + wave * 512;             // + issue*2048 halves
    _Float16* lB = Bs + wave * 512;

    const int q4 = lane >> 4, l15 = lane & 15;
    int aoff[4], boff[4];
#pragma unroll
    for (int i = 0; i < 4; ++i) {
        int rA = wm * 64 + i * 16 + l15;
        aoff[i] = rA * 64 + ((q4 ^ (rA & 7)) * 8);
        int rB = wn * 64 + i * 16 + l15;
        boff[i] = rB * 64 + ((q4 ^ (rB & 7)) * 8);
    }

    floatx4 zero = {0.f, 0.f, 0.f, 0.f};
    floatx4 acc[4][4];
#pragma unroll
    for (int mi = 0; mi < 4; ++mi)
#pragma unroll
        for (int ni = 0; ni < 4; ++ni) acc[mi][ni] = zero;

    for (int kt = 0; kt < H_DIM; kt += 64) {
        __syncthreads();
#pragma unroll
        for (int i = 0; i < 4; ++i) {
            async_cp16(ag + kt + (size_t)i * 32 * H_DIM, lA + i * 2048);
            async_cp16(bg + kt + (size_t)i * 32 * H_DIM, lB + i * 2048);
        }
        __syncthreads();
#pragma unroll
        for (int kk = 0; kk < 2; ++kk) {
            half8 af[4], bf[4];
#pragma unroll
            for (int i = 0; i < 4; ++i) af[i] = *(const half8*)(As + (aoff[i] ^ (kk * 32)));
#pragma unroll
            for (int i = 0; i < 4; ++i) bf[i] = *(const half8*)(Bs + (boff[i] ^ (kk * 32)));
#pragma unroll
            for (int mi = 0; mi < 4; ++mi)
#pragma unroll
                for (int ni = 0; ni < 4; ++ni)
                    acc[mi][ni] = __builtin_amdgcn_mfma_f32_16x16x32_f16(af[mi], bf[ni], acc[mi][ni], 0, 0, 0);
        }
    }

    // epilogue: ni 0,1 = gate, ni 2,3 = up of the same h-columns
    const int rq = q4 * 4;
#pragma unroll
    for (int mi = 0; mi < 4; ++mi)
#pragma unroll
        for (int nc = 0; nc < 2; ++nc)
#pragma unroll
            for (int r = 0; r < 4; ++r) {
                int row = m0 + wm * 64 + mi * 16 + rq + r;
                int col = blockIdx.y * 64 + wn * 32 + nc * 16 + l15;
                float g = acc[mi][nc][r];
                float u = acc[mi][nc + 2][r];
                float s = (g / (1.0f + __expf(-g))) * u;
                h[(size_t)row * I_DIM + col] = (_Float16)s;
            }
}

// -------- GEMM2: out = h @ Wd, fp32 out --------
__launch_bounds__(256, 3)
__global__ void gemm_down(const _Float16* __restrict__ A,    // h [T][I]
                          const _Float16* __restrict__ B,    // Wd_t [H][I]
                          float* __restrict__ out) {         // [T][H]
    __shared__ _Float16 As[128 * 64];
    __shared__ _Float16 Bs[128 * 64];
    const int t = threadIdx.x;
    const int wave = t >> 6, lane = t & 63;
    const int m0 = blockIdx.x * 128;
    const int n0 = blockIdx.y * 128;
    const int wm = wave >> 1, wn = wave & 1;

    const int srow = wave * 8 + (lane >> 3);
    const int schunk = (lane & 7) ^ (lane >> 3);
    const _Float16* ag = A + (size_t)(m0 + srow) * I_DIM + schunk * 8;
    const _Float16* bg = B + (size_t)(n0 + srow) * I_DIM + schunk * 8;
    _Float16* lA = As + wave * 512;
    _Float16* lB = Bs + wave * 512;

    const int q4 = lane >> 4, l15 = lane & 15;
    int aoff[4], boff[4];
#pragma unroll
    for (int i = 0; i < 4; ++i) {
        int rA = wm * 64 + i * 16 + l15;
        aoff[i] = rA * 64 + ((q4 ^ (rA & 7)) * 8);
        int rB = wn * 64 + i * 16 + l15;
        boff[i] = rB * 64 + ((q4 ^ (rB & 7)) * 8);
    }

    floatx4 zero = {0.f, 0.f, 0.f, 0.f};
    floatx4 acc[4][4];
#pragma unroll
    for (int mi = 0; mi < 4; ++mi)
#pragma unroll
        for (int ni = 0; ni < 4; ++ni) acc[mi][ni] = zero;

    for (int kt = 0; kt < I_DIM; kt += 64) {
        __syncthreads();
#pragma unroll
        for (int i = 0; i < 4; ++i) {
            async_cp16(ag + kt + (size_t)i * 32 * I_DIM, lA + i * 2048);
            async_cp16(bg + kt + (size_t)i * 32 * I_DIM, lB + i * 2048);
        }
        __syncthreads();
#pragma unroll
        for (int kk = 0; kk < 2; ++kk) {
            half8 af[4], bf[4];
#pragma unroll
            for (int i = 0; i < 4; ++i) af[i] = *(const half8*)(As + (aoff[i] ^ (kk * 32)));
#pragma unroll
            for (int i = 0; i < 4; ++i) bf[i] = *(const half8*)(Bs + (boff[i] ^ (kk * 32)));
#pragma unroll
            for (int mi = 0; mi < 4; ++mi)
#pragma unroll
                for (int ni = 0; ni < 4; ++ni)
                    acc[mi][ni] = __builtin_amdgcn_mfma_f32_16x16x32_f16(af[mi], bf[ni], acc[mi][ni], 0, 0, 0);
        }
    }

    const int rq = q4 * 4;
#pragma unroll
    for (int mi = 0; mi < 4; ++mi)
#pragma unroll
        for (int ni = 0; ni < 4; ++ni)
#pragma unroll
            for (int r = 0; r < 4; ++r) {
                int row = m0 + wm * 64 + mi * 16 + rq + r;
                int col = n0 + wn * 64 + ni * 16 + l15;
                out[(size_t)row * H_DIM + col] = acc[ni][mi][r]; // placeholder guard; fixed below
            }
}

// NOTE: the line above would transpose output; correct indexing is acc[mi][ni][r].
// To keep a single definitive kernel, we re-define via a fixed copy:

__launch_bounds__(256, 3)
__global__ void gemm_down_fixed(const _Float16* __restrict__ A,
                                const _Float16* __restrict__ B,
                                float* __restrict__ out) {
    __shared__ _Float16 As[128 * 64];
    __shared__ _Float16 Bs[128 * 64];
    const int t = threadIdx.x;
    const int wave = t >> 6, lane = t & 63;
    const int m0 = blockIdx.x * 128;
    const int n0 = blockIdx.y * 128;
    const int wm = wave >> 1, wn = wave & 1;

    const int srow = wave * 8 + (lane >> 3);
    const int schunk = (lane & 7) ^ (lane >> 3);
    const _Float16* ag = A + (size_t)(m0 + srow) * I_DIM + schunk * 8;
    const _Float16* bg = B + (size_t)(n0 + srow) * I_DIM + schunk * 8;
    _Float16* lA = As + wave * 512;
    _Float16* lB = Bs + wave * 512;

    const int q4 = lane >> 4, l15 = lane & 15;
    int aoff[4], boff[4];
#pragma unroll
    for (int i = 0; i < 4; ++i) {
        int rA = wm * 64 + i * 16 + l15;
        aoff[i] = rA * 64 + ((q4 ^ (rA & 7)) * 8);
        int rB = wn * 64 + i * 16 + l15;
        boff[i] = rB * 64 + ((q4 ^ (rB & 7)) * 8);
    }

    floatx4 zero = {0.f, 0.f, 0.f, 0.f};
    floatx4 acc[4][4];
#pragma unroll
    for (int mi = 0; mi < 4; ++mi)
#pragma unroll
        for (int ni = 0; ni < 4; ++ni) acc[mi][ni] = zero;

    for (int kt = 0; kt < I_DIM; kt += 64) {
        __syncthreads();
#pragma unroll
        for (int i = 0; i < 4; ++i) {
            async_cp16(ag + kt + (size_t)i * 32 * I_DIM, lA + i * 2048);
            async_cp16(bg + kt + (size_t)i * 32 * I_DIM, lB + i * 2048);
        }
        __syncthreads();
#pragma unroll
        for (int kk = 0; kk < 2; ++kk) {
            half8 af[4], bf[4];
#pragma unroll
            for (int i = 0; i < 4; ++i) af[i] = *(const half8*)(As + (aoff[i] ^ (kk * 32)));
#pragma unroll
            for (int i = 0; i < 4; ++i) bf[i] = *(const half8*)(Bs + (boff[i] ^ (kk * 32)));
#pragma unroll
            for (int mi = 0; mi < 4; ++mi)
#pragma unroll
                for (int ni = 0; ni < 4; ++ni)
                    acc[mi][ni] = __builtin_amdgcn_mfma_f32_16x16x32_f16(af[mi], bf[ni], acc[mi][ni], 0, 0, 0);
        }
    }

    const int rq = q4 * 4;
#pragma unroll
    for (int mi = 0; mi < 4; ++mi)
#pragma unroll
        for (int ni = 0; ni < 4; ++ni)
#pragma unroll
            for (int r = 0; r < 4; ++r) {
                int row = m0 + wm * 64 + mi * 16 + rq + r;
                int col = n0 + wn * 64 + ni * 16 + l15;
                out[(size_t)row * H_DIM + col] = acc[mi][ni][r];
            }
}

extern "C" void kernel_launch(void* const* d_in, const int* in_sizes, int n_in,
                              void* d_out, int out_size, void* d_ws, size_t ws_size,
                              hipStream_t stream) {
    const float* x    = (const float*)d_in[0];
    const int* qw_g   = (const int*)d_in[1];
    const int* qz_g   = (const int*)d_in[2];
    const float* sc_g = (const float*)d_in[3];
    const int* qw_u   = (const int*)d_in[4];
    const int* qz_u   = (const int*)d_in[5];
    const float* sc_u = (const float*)d_in[6];
    const int* qw_d   = (const int*)d_in[7];
    const int* qz_d   = (const int*)d_in[8];
    const float* sc_d = (const float*)d_in[9];
    float* out = (float*)d_out;

    // ws (fp16): xh 64MiB | h 44MiB | B' 11MiB | Wd_t 5.5MiB
    char* ws = (char*)d_ws;
    _Float16* xh  = (_Float16*)ws;  ws += (size_t)T_DIM * H_DIM * sizeof(_Float16);
    _Float16* hh  = (_Float16*)ws;  ws += (size_t)T_DIM * I_DIM * sizeof(_Float16);
    _Float16* Bgu = (_Float16*)ws;  ws += (size_t)NB_DIM * H_DIM * sizeof(_Float16);
    _Float16* Wd  = (_Float16*)ws;  ws += (size_t)H_DIM * I_DIM * sizeof(_Float16);

    cvt_fp16_kernel<<<(T_DIM * H_DIM) / 2048, 256, 0, stream>>>(x, xh);
    dequant_kernel<<<dim3(I_DIM / 64, H_DIM / 32), 256, 0, stream>>>(qw_g, qz_g, sc_g, Bgu, H_DIM, I_DIM, 1, 0);
    dequant_kernel<<<dim3(I_DIM / 64, H_DIM / 32), 256, 0, stream>>>(qw_u, qz_u, sc_u, Bgu, H_DIM, I_DIM, 1, 32);
    dequant_kernel<<<dim3(H_DIM / 64, I_DIM / 32), 256, 0, stream>>>(qw_d, qz_d, sc_d, Wd, I_DIM, H_DIM, 0, 0);
    gemm_gateup<<<dim3(T_DIM / 128, NB_DIM / 128), 256, 0, stream>>>(xh, Bgu, hh);
    gemm_down_fixed<<<dim3(T_DIM / 128, H_DIM / 128), 256, 0, stream>>>(hh, Wd, out);
}